// Round 5
// baseline (5085.859 us; speedup 1.0000x reference)
//
#include <hip/hip_runtime.h>
#include <math.h>

#define TLEN 256
#define NB   32
#define HID  512
#define VOC  1024

typedef __attribute__((ext_vector_type(16))) float sf16;

// ---- device-coherent (agent-scope) Z accessors ----
__device__ __forceinline__ float zload(const float* p) {
    return __hip_atomic_load(p, __ATOMIC_RELAXED, __HIP_MEMORY_SCOPE_AGENT);
}
__device__ __forceinline__ void zstore(float* p, float v) {
    __hip_atomic_store(p, v, __ATOMIC_RELAXED, __HIP_MEMORY_SCOPE_AGENT);
}

// ---------------- GEMM: logits = enc @ W^T + bias (~80 us, leave alone) ----------------
__global__ __launch_bounds__(256) void gemm_logits2(
    const float* __restrict__ A, const float* __restrict__ W,
    const float* __restrict__ bias, float* __restrict__ C)
{
    const int K = HID, N = VOC;
    __shared__ float As[16][132];
    __shared__ float Ws[16][132];
    int tid = threadIdx.x;
    int row0 = blockIdx.y << 7;
    int col0 = blockIdx.x << 7;
    int tx = tid & 15, ty = tid >> 4;
    int lr = tid >> 2;
    int lk = (tid & 3) << 2;
    float acc[8][8] = {};
    float bj[8];
    #pragma unroll
    for (int j = 0; j < 8; ++j) bj[j] = bias[col0 + tx * 8 + j];

    for (int k0 = 0; k0 < K; k0 += 16) {
        float4 av0 = *(const float4*)(A + (size_t)(row0 + lr) * K + k0 + lk);
        float4 av1 = *(const float4*)(A + (size_t)(row0 + lr + 64) * K + k0 + lk);
        float4 wv0 = *(const float4*)(W + (size_t)(col0 + lr) * K + k0 + lk);
        float4 wv1 = *(const float4*)(W + (size_t)(col0 + lr + 64) * K + k0 + lk);
        __syncthreads();
        As[lk+0][lr] = av0.x; As[lk+1][lr] = av0.y; As[lk+2][lr] = av0.z; As[lk+3][lr] = av0.w;
        As[lk+0][lr+64] = av1.x; As[lk+1][lr+64] = av1.y; As[lk+2][lr+64] = av1.z; As[lk+3][lr+64] = av1.w;
        Ws[lk+0][lr] = wv0.x; Ws[lk+1][lr] = wv0.y; Ws[lk+2][lr] = wv0.z; Ws[lk+3][lr] = wv0.w;
        Ws[lk+0][lr+64] = wv1.x; Ws[lk+1][lr+64] = wv1.y; Ws[lk+2][lr+64] = wv1.z; Ws[lk+3][lr+64] = wv1.w;
        __syncthreads();
        #pragma unroll
        for (int k = 0; k < 16; ++k) {
            float4 a0 = *(const float4*)&As[k][ty * 8];
            float4 a1 = *(const float4*)&As[k][ty * 8 + 4];
            float4 w0 = *(const float4*)&Ws[k][tx * 8];
            float4 w1 = *(const float4*)&Ws[k][tx * 8 + 4];
            float ar[8] = {a0.x, a0.y, a0.z, a0.w, a1.x, a1.y, a1.z, a1.w};
            float wr[8] = {w0.x, w0.y, w0.z, w0.w, w1.x, w1.y, w1.z, w1.w};
            #pragma unroll
            for (int i = 0; i < 8; ++i)
                #pragma unroll
                for (int j = 0; j < 8; ++j)
                    acc[i][j] = fmaf(ar[i], wr[j], acc[i][j]);
        }
    }
    #pragma unroll
    for (int i = 0; i < 8; ++i) {
        size_t r = row0 + ty * 8 + i;
        float4 o0, o1;
        o0.x = acc[i][0] + bj[0]; o0.y = acc[i][1] + bj[1];
        o0.z = acc[i][2] + bj[2]; o0.w = acc[i][3] + bj[3];
        o1.x = acc[i][4] + bj[4]; o1.y = acc[i][5] + bj[5];
        o1.z = acc[i][6] + bj[6]; o1.w = acc[i][7] + bj[7];
        *(float4*)(C + r * N + col0 + tx * 8)     = o0;
        *(float4*)(C + r * N + col0 + tx * 8 + 4) = o1;
    }
}

// ---------------- E = exp(transition) ----------------
__global__ __launch_bounds__(256) void exp_kernel(
    const float* __restrict__ in, float* __restrict__ out, int n4)
{
    int i = blockIdx.x * 256 + threadIdx.x;
    if (i < n4) {
        float4 v = ((const float4*)in)[i];
        float4 r;
        r.x = __expf(v.x); r.y = __expf(v.y); r.z = __expf(v.z); r.w = __expf(v.w);
        ((float4*)out)[i] = r;
    }
}

// ---------------- persistent CRF scan v3: p in SGPRs via s_load ----------------
// grid (8 bg, 16 cc), 1024 threads = 16 waves. Wave w covers v in [w*64, w*64+64).
// p[v][4 batches] lives in a block-private GLOBAL buffer; compute waves fetch it
// with s_load_dwordx16 (scalar K$ path) -> FMA is v_fmac(vacc, s_p, v_e): DS pipe idle.
// s_dcache_inv per step: K$ is not coherent with the vector stores that rewrote p.
__global__ __launch_bounds__(1024) void crf_scan(
    const float* __restrict__ logits, float* __restrict__ Za, float* __restrict__ Zb,
    const float* __restrict__ E, const int* __restrict__ lengths,
    unsigned int* __restrict__ cnt, float* __restrict__ pglob)
{
    __shared__ float m4[4];
    __shared__ float Sred[16][64][5];   // [wave][col][batch], +1 pad
    int tid  = threadIdx.x;
    int w    = tid >> 6;
    int lane = tid & 63;
    int bg   = blockIdx.x;              // linear id = bg + 8*cc -> all cc of a bg share an XCD
    int cc   = blockIdx.y;
    int b0   = bg * 4;
    float* pbuf = pglob + (size_t)(bg * 16 + cc) * (VOC * 4);   // block-private 16 KB

    // wave-uniform SGPR base address of this wave's p chunk (v0*4 floats in)
    int v0 = w << 6;
    unsigned long long pa64 = (unsigned long long)(pbuf + v0 * 4);
    unsigned int plo = __builtin_amdgcn_readfirstlane((unsigned int)(pa64 & 0xffffffffull));
    unsigned int phi = __builtin_amdgcn_readfirstlane((unsigned int)(pa64 >> 32));
    unsigned long long pu = (((unsigned long long)phi) << 32) | plo;

    int len4[4];
    #pragma unroll
    for (int i = 0; i < 4; ++i) len4[i] = lengths[b0 + i];
    int lmax = max(max(len4[0], len4[1]), max(len4[2], len4[3]));

    const float* src = logits;          // Z0 = logits[t=0] (rows 0..31)
    for (int t = 1; t < TLEN; ++t) {
        float* dst = (t & 1) ? Za : Zb;
        if (t >= lmax) {                // uniform across this bg's 16 blocks
            if (src != Za && tid < 256) {
                int bl = tid >> 6, cl = tid & 63;
                int b = b0 + bl, cg = (cc << 6) + cl;
                Za[b * VOC + cg] = zload(&src[b * VOC + cg]);
            }
            return;
        }
        // (A) staging: waves 0..3 compute m_b and write p[v][b] to global pbuf
        if (w < 4) {
            const float* zrow = src + (b0 + w) * VOC;
            float zv[16];
            float m = -1e30f;
            #pragma unroll
            for (int i = 0; i < 16; ++i) { zv[i] = zload(&zrow[lane + (i << 6)]); m = fmaxf(m, zv[i]); }
            #pragma unroll
            for (int off = 32; off; off >>= 1) m = fmaxf(m, __shfl_xor(m, off));
            #pragma unroll
            for (int i = 0; i < 16; ++i) pbuf[(lane + (i << 6)) * 4 + w] = __expf(zv[i] - m);
            if (lane == 0) m4[w] = m;
        }
        __syncthreads();                            // drains vmcnt(0): p stores in L2
        asm volatile("s_dcache_inv" ::: "memory");  // drop stale K$ lines of pbuf

        // (B) compute: wave w, 64 v, col c; p from SGPRs, e from VMEM
        int c = (cc << 6) + lane;
        const float* Ec = E + c;
        float a0 = 0.f, a1 = 0.f, a2 = 0.f, a3 = 0.f;
        #pragma unroll
        for (int ch = 0; ch < 8; ++ch) {            // 8 chunks x 8 v
            sf16 pa, pb;
            asm volatile("s_load_dwordx16 %0, %2, %3\n\t"
                         "s_load_dwordx16 %1, %2, %4\n\t"
                         "s_waitcnt lgkmcnt(0)"
                         : "=s"(pa), "=s"(pb)
                         : "s"(pu), "i"(ch * 128), "i"(ch * 128 + 64));
            const float* Ev = Ec + ((size_t)(v0 + ch * 8) << 10);
            #pragma unroll
            for (int vv = 0; vv < 4; ++vv) {
                float e = Ev[(size_t)vv << 10];
                a0 = fmaf(e, pa[vv * 4 + 0], a0);
                a1 = fmaf(e, pa[vv * 4 + 1], a1);
                a2 = fmaf(e, pa[vv * 4 + 2], a2);
                a3 = fmaf(e, pa[vv * 4 + 3], a3);
            }
            #pragma unroll
            for (int vv = 0; vv < 4; ++vv) {
                float e = Ev[(size_t)(vv + 4) << 10];
                a0 = fmaf(e, pb[vv * 4 + 0], a0);
                a1 = fmaf(e, pb[vv * 4 + 1], a1);
                a2 = fmaf(e, pb[vv * 4 + 2], a2);
                a3 = fmaf(e, pb[vv * 4 + 3], a3);
            }
        }
        Sred[w][lane][0] = a0;
        Sred[w][lane][1] = a1;
        Sred[w][lane][2] = a2;
        Sred[w][lane][3] = a3;
        __syncthreads();

        // (C) finalize: 256 threads, 4 batches x 64 cols
        if (tid < 256) {
            int bl = tid >> 6, cl = tid & 63;
            float S = 0.f;
            #pragma unroll
            for (int ww = 0; ww < 16; ++ww) S += Sred[ww][cl][bl];
            int b  = b0 + bl;
            int cg = (cc << 6) + cl;
            float outv;
            if (t < len4[bl]) outv = logits[((size_t)t * NB + b) * VOC + cg] + m4[bl] + __logf(S);
            else              outv = zload(&src[b * VOC + cg]);
            zstore(&dst[b * VOC + cg], outv);
        }

        // (D) inter-block barrier for this bg (syncthreads drains vmcnt first)
        __syncthreads();
        if (tid == 0) {
            unsigned int* c16 = &cnt[t * 8 + bg];
            __hip_atomic_fetch_add(c16, 1u, __ATOMIC_RELAXED, __HIP_MEMORY_SCOPE_AGENT);
            while (__hip_atomic_load(c16, __ATOMIC_RELAXED, __HIP_MEMORY_SCOPE_AGENT) < 16u)
                __builtin_amdgcn_s_sleep(1);
        }
        __syncthreads();
        src = dst;
    }
}

// ---------------- epilogue ----------------
__global__ __launch_bounds__(256) void crf_finish(
    const float* __restrict__ Zfin, const float* __restrict__ logits,
    const float* __restrict__ trans, const int* __restrict__ targets,
    const int* __restrict__ lengths, float* __restrict__ out)
{
    __shared__ float part[NB];
    int tid = threadIdx.x;
    int b = tid >> 3, j = tid & 7;
    const float* zr = Zfin + (size_t)b * VOC;
    float m = -1e30f;
    for (int v = j; v < VOC; v += 8) m = fmaxf(m, zr[v]);
    #pragma unroll
    for (int off = 1; off < 8; off <<= 1) m = fmaxf(m, __shfl_xor(m, off));
    float s = 0.f;
    for (int v = j; v < VOC; v += 8) s += __expf(zr[v] - m);
    #pragma unroll
    for (int off = 1; off < 8; off <<= 1) s += __shfl_xor(s, off);
    float logZ = m + __logf(s);
    int len = lengths[b];
    float acc = 0.f;
    for (int t = j; t < TLEN; t += 8) {
        if (t < len) {
            int tg = targets[t * NB + b];
            acc += logits[((size_t)t * NB + b) * VOC + tg];
            if (t >= 1) acc += trans[(size_t)targets[(t - 1) * NB + b] * VOC + tg];
        }
    }
    #pragma unroll
    for (int off = 1; off < 8; off <<= 1) acc += __shfl_xor(acc, off);
    if (j == 0) part[b] = logZ - acc;
    __syncthreads();
    if (tid == 0) {
        float sum = 0.f;
        #pragma unroll
        for (int i = 0; i < NB; ++i) sum += part[i];
        out[0] = sum / (float)NB;
    }
}

extern "C" void kernel_launch(void* const* d_in, const int* in_sizes, int n_in,
                              void* d_out, int out_size, void* d_ws, size_t ws_size,
                              hipStream_t stream)
{
    const float* enc   = (const float*)d_in[0];
    const float* W     = (const float*)d_in[1];
    const float* bias  = (const float*)d_in[2];
    const float* trans = (const float*)d_in[3];
    const int* targets = (const int*)d_in[4];
    const int* lengths = (const int*)d_in[5];
    float* out = (float*)d_out;

    // ws: logits 33.5MB | E 4MB | Za 128KB | Zb 128KB | cnt 8KB | pglob 2MB
    float* ws     = (float*)d_ws;
    float* logits = ws;
    float* E      = logits + (size_t)TLEN * NB * VOC;
    float* Za     = E + (size_t)VOC * VOC;
    float* Zb     = Za + (size_t)NB * VOC;
    unsigned int* cnt = (unsigned int*)(Zb + (size_t)NB * VOC);
    float* pglob  = (float*)(cnt + TLEN * 8) + 8;   // keep 32B apart from cnt

    hipMemsetAsync(cnt, 0, TLEN * 8 * sizeof(unsigned int), stream);
    gemm_logits2<<<dim3(VOC / 128, TLEN * NB / 128), 256, 0, stream>>>(enc, W, bias, logits);
    exp_kernel<<<dim3((VOC * VOC / 4 + 255) / 256), 256, 0, stream>>>(trans, E, VOC * VOC / 4);
    crf_scan<<<dim3(8, 16), 1024, 0, stream>>>(logits, Za, Zb, E, lengths, cnt, pglob);
    crf_finish<<<1, 256, 0, stream>>>(Za, logits, trans, targets, lengths, out);
}

// Round 7
// 1072.375 us; speedup vs baseline: 4.7426x; 4.7426x over previous
//
#include <hip/hip_runtime.h>
#include <math.h>
#include <stdint.h>

#define TLEN 256
#define NB   32
#define HID  512
#define VOC  1024

typedef __attribute__((ext_vector_type(2))) _Float16 half2_t;
typedef __attribute__((ext_vector_type(2))) __fp16  pk16_t;

// ---- device-coherent (agent-scope) Z accessors ----
__device__ __forceinline__ float zload(const float* p) {
    return __hip_atomic_load(p, __ATOMIC_RELAXED, __HIP_MEMORY_SCOPE_AGENT);
}
__device__ __forceinline__ float2 zload2(const float* p) {
    unsigned long long u = __hip_atomic_load((const unsigned long long*)p,
                                             __ATOMIC_RELAXED, __HIP_MEMORY_SCOPE_AGENT);
    union { unsigned long long u; float2 f; } c; c.u = u; return c.f;
}
__device__ __forceinline__ void zstore(float* p, float v) {
    __hip_atomic_store(p, v, __ATOMIC_RELAXED, __HIP_MEMORY_SCOPE_AGENT);
}
__device__ __forceinline__ uint32_t pack_pkrtz(float a, float b) {
    pk16_t h = __builtin_amdgcn_cvt_pkrtz(a, b);
    return __builtin_bit_cast(uint32_t, h);
}
__device__ __forceinline__ float fdot2u(uint32_t a, uint32_t b, float acc) {
    half2_t ha = __builtin_bit_cast(half2_t, a);
    half2_t hb = __builtin_bit_cast(half2_t, b);
    return __builtin_amdgcn_fdot2(ha, hb, acc, false);
}

// ---------------- GEMM: logits = enc @ W^T + bias (~80 us) ----------------
__global__ __launch_bounds__(256) void gemm_logits2(
    const float* __restrict__ A, const float* __restrict__ W,
    const float* __restrict__ bias, float* __restrict__ C)
{
    const int K = HID, N = VOC;
    __shared__ float As[16][132];
    __shared__ float Ws[16][132];
    int tid = threadIdx.x;
    int row0 = blockIdx.y << 7;
    int col0 = blockIdx.x << 7;
    int tx = tid & 15, ty = tid >> 4;
    int lr = tid >> 2;
    int lk = (tid & 3) << 2;
    float acc[8][8] = {};
    float bj[8];
    #pragma unroll
    for (int j = 0; j < 8; ++j) bj[j] = bias[col0 + tx * 8 + j];

    for (int k0 = 0; k0 < K; k0 += 16) {
        float4 av0 = *(const float4*)(A + (size_t)(row0 + lr) * K + k0 + lk);
        float4 av1 = *(const float4*)(A + (size_t)(row0 + lr + 64) * K + k0 + lk);
        float4 wv0 = *(const float4*)(W + (size_t)(col0 + lr) * K + k0 + lk);
        float4 wv1 = *(const float4*)(W + (size_t)(col0 + lr + 64) * K + k0 + lk);
        __syncthreads();
        As[lk+0][lr] = av0.x; As[lk+1][lr] = av0.y; As[lk+2][lr] = av0.z; As[lk+3][lr] = av0.w;
        As[lk+0][lr+64] = av1.x; As[lk+1][lr+64] = av1.y; As[lk+2][lr+64] = av1.z; As[lk+3][lr+64] = av1.w;
        Ws[lk+0][lr] = wv0.x; Ws[lk+1][lr] = wv0.y; Ws[lk+2][lr] = wv0.z; Ws[lk+3][lr] = wv0.w;
        Ws[lk+0][lr+64] = wv1.x; Ws[lk+1][lr+64] = wv1.y; Ws[lk+2][lr+64] = wv1.z; Ws[lk+3][lr+64] = wv1.w;
        __syncthreads();
        #pragma unroll
        for (int k = 0; k < 16; ++k) {
            float4 a0 = *(const float4*)&As[k][ty * 8];
            float4 a1 = *(const float4*)&As[k][ty * 8 + 4];
            float4 w0 = *(const float4*)&Ws[k][tx * 8];
            float4 w1 = *(const float4*)&Ws[k][tx * 8 + 4];
            float ar[8] = {a0.x, a0.y, a0.z, a0.w, a1.x, a1.y, a1.z, a1.w};
            float wr[8] = {w0.x, w0.y, w0.z, w0.w, w1.x, w1.y, w1.z, w1.w};
            #pragma unroll
            for (int i = 0; i < 8; ++i)
                #pragma unroll
                for (int j = 0; j < 8; ++j)
                    acc[i][j] = fmaf(ar[i], wr[j], acc[i][j]);
        }
    }
    #pragma unroll
    for (int i = 0; i < 8; ++i) {
        size_t r = row0 + ty * 8 + i;
        float4 o0, o1;
        o0.x = acc[i][0] + bj[0]; o0.y = acc[i][1] + bj[1];
        o0.z = acc[i][2] + bj[2]; o0.w = acc[i][3] + bj[3];
        o1.x = acc[i][4] + bj[4]; o1.y = acc[i][5] + bj[5];
        o1.z = acc[i][6] + bj[6]; o1.w = acc[i][7] + bj[7];
        *(float4*)(C + r * N + col0 + tx * 8)     = o0;
        *(float4*)(C + r * N + col0 + tx * 8 + 4) = o1;
    }
}

// ---------------- Epk[v2][c] = half2(exp(trans[2v2][c]), exp(trans[2v2+1][c])) ----------------
__global__ __launch_bounds__(256) void exp_pack(
    const float* __restrict__ trans, uint32_t* __restrict__ Epk)
{
    int idx = blockIdx.x * 256 + threadIdx.x;       // over 512*1024
    int v2 = idx >> 10, c = idx & 1023;
    float e0 = __expf(trans[(size_t)(2 * v2) * VOC + c]);
    float e1 = __expf(trans[(size_t)(2 * v2 + 1) * VOC + c]);
    Epk[idx] = pack_pkrtz(e0, e1);
}

// ---------------- persistent CRF scan v4: f16 dot2, 2 batches/block ----------------
// grid (16 bg, 16 cc), 512 thr = 8 waves. Block: batches {2bg,2bg+1} x 64 cols.
// p packed half2-over-v in LDS pst[v2][2 batches]; inner op v_dot2_f32_f16.
// One b128 LDS read = 2 v-pairs x 2 batches -> DS reads/CU ~3.1K cyc/step.
__global__ __launch_bounds__(512) void crf_scan(
    const float* __restrict__ logits, float* __restrict__ Za, float* __restrict__ Zb,
    const uint32_t* __restrict__ Epk, const int* __restrict__ lengths,
    unsigned int* __restrict__ cnt)
{
    __shared__ uint32_t pst[VOC / 2][2];   // 4 KB: [v2][local batch] packed half2
    __shared__ float m2[2];
    __shared__ float Sred[8][64][3];       // [wave][col][batch], +1 pad
    int tid  = threadIdx.x;
    int w    = tid >> 6;
    int lane = tid & 63;
    int bg   = blockIdx.x;                 // linear = bg + 16*cc -> XCD = bg%8 (heuristic)
    int cc   = blockIdx.y;
    int b0   = bg * 2;

    int len2[2];
    len2[0] = lengths[b0];
    len2[1] = lengths[b0 + 1];
    int lmax = max(len2[0], len2[1]);

    const float* src = logits;             // Z0 = logits[t=0] (rows 0..31)
    for (int t = 1; t < TLEN; ++t) {
        float* dst = (t & 1) ? Za : Zb;
        if (t >= lmax) {                   // uniform across this bg's 16 blocks
            if (src != Za && tid < 128) {  // park final Z into Za
                int bl = tid >> 6, cl = tid & 63;
                int b = b0 + bl, cg = (cc << 6) + cl;
                Za[b * VOC + cg] = zload(&src[b * VOC + cg]);
            }
            return;
        }
        // (A) staging: waves 0,1 compute m_b and packed p for batch b0+w
        if (w < 2) {
            const float* zrow = src + (b0 + w) * VOC;
            float2 zv[8];
            float m = -1e30f;
            #pragma unroll
            for (int i = 0; i < 8; ++i) {
                zv[i] = zload2(&zrow[(lane + (i << 6)) * 2]);
                m = fmaxf(m, fmaxf(zv[i].x, zv[i].y));
            }
            #pragma unroll
            for (int off = 32; off; off >>= 1) m = fmaxf(m, __shfl_xor(m, off));
            #pragma unroll
            for (int i = 0; i < 8; ++i)
                pst[lane + (i << 6)][w] = pack_pkrtz(__expf(zv[i].x - m), __expf(zv[i].y - m));
            if (lane == 0) m2[w] = m;
        }
        __syncthreads();                   // (B)

        // (C) wave w: partial S over v2 in [w*64, w*64+64), 64 cols x 2 batches
        int c = (cc << 6) + lane;
        const uint32_t* Ep = Epk + c;
        int v20 = w << 6;
        float a0 = 0.f, a1 = 0.f;
        #pragma unroll 8
        for (int j = 0; j < 64; j += 2) {
            int v2 = v20 + j;
            uint4 pq = *(const uint4*)&pst[v2][0];        // (v2,b0)(v2,b1)(v2+1,b0)(v2+1,b1)
            uint32_t e0 = Ep[(size_t)v2 << 10];
            uint32_t e1 = Ep[(size_t)(v2 + 1) << 10];
            a0 = fdot2u(pq.x, e0, a0);
            a1 = fdot2u(pq.y, e0, a1);
            a0 = fdot2u(pq.z, e1, a0);
            a1 = fdot2u(pq.w, e1, a1);
        }
        Sred[w][lane][0] = a0;
        Sred[w][lane][1] = a1;
        __syncthreads();                   // (D)

        // (E) finalize: 128 threads, 2 batches x 64 cols
        if (tid < 128) {
            int bl = tid >> 6, cl = tid & 63;
            float S = 0.f;
            #pragma unroll
            for (int ww = 0; ww < 8; ++ww) S += Sred[ww][cl][bl];
            int b  = b0 + bl;
            int cg = (cc << 6) + cl;
            float outv;
            if (t < len2[bl]) outv = logits[((size_t)t * NB + b) * VOC + cg] + m2[bl] + __logf(S);
            else              outv = zload(&src[b * VOC + cg]);
            zstore(&dst[b * VOC + cg], outv);
        }

        // (F) inter-block barrier among this bg's 16 blocks
        __syncthreads();                   // drains vmcnt(0): Z stores visible
        if (tid == 0) {
            unsigned int* c16 = &cnt[t * 16 + bg];
            __hip_atomic_fetch_add(c16, 1u, __ATOMIC_RELAXED, __HIP_MEMORY_SCOPE_AGENT);
            while (__hip_atomic_load(c16, __ATOMIC_RELAXED, __HIP_MEMORY_SCOPE_AGENT) < 16u)
                __builtin_amdgcn_s_sleep(1);
        }
        __syncthreads();
        src = dst;
    }
}

// ---------------- epilogue ----------------
__global__ __launch_bounds__(256) void crf_finish(
    const float* __restrict__ Zfin, const float* __restrict__ logits,
    const float* __restrict__ trans, const int* __restrict__ targets,
    const int* __restrict__ lengths, float* __restrict__ out)
{
    __shared__ float part[NB];
    int tid = threadIdx.x;
    int b = tid >> 3, j = tid & 7;
    const float* zr = Zfin + (size_t)b * VOC;
    float m = -1e30f;
    for (int v = j; v < VOC; v += 8) m = fmaxf(m, zr[v]);
    #pragma unroll
    for (int off = 1; off < 8; off <<= 1) m = fmaxf(m, __shfl_xor(m, off));
    float s = 0.f;
    for (int v = j; v < VOC; v += 8) s += __expf(zr[v] - m);
    #pragma unroll
    for (int off = 1; off < 8; off <<= 1) s += __shfl_xor(s, off);
    float logZ = m + __logf(s);
    int len = lengths[b];
    float acc = 0.f;
    for (int t = j; t < TLEN; t += 8) {
        if (t < len) {
            int tg = targets[t * NB + b];
            acc += logits[((size_t)t * NB + b) * VOC + tg];
            if (t >= 1) acc += trans[(size_t)targets[(t - 1) * NB + b] * VOC + tg];
        }
    }
    #pragma unroll
    for (int off = 1; off < 8; off <<= 1) acc += __shfl_xor(acc, off);
    if (j == 0) part[b] = logZ - acc;
    __syncthreads();
    if (tid == 0) {
        float sum = 0.f;
        #pragma unroll
        for (int i = 0; i < NB; ++i) sum += part[i];
        out[0] = sum / (float)NB;
    }
}

extern "C" void kernel_launch(void* const* d_in, const int* in_sizes, int n_in,
                              void* d_out, int out_size, void* d_ws, size_t ws_size,
                              hipStream_t stream)
{
    const float* enc   = (const float*)d_in[0];
    const float* W     = (const float*)d_in[1];
    const float* bias  = (const float*)d_in[2];
    const float* trans = (const float*)d_in[3];
    const int* targets = (const int*)d_in[4];
    const int* lengths = (const int*)d_in[5];
    float* out = (float*)d_out;

    // ws: logits 33.5MB | Epk 2MB | Za 128KB | Zb 128KB | cnt 16KB
    float* ws     = (float*)d_ws;
    float* logits = ws;
    uint32_t* Epk = (uint32_t*)(logits + (size_t)TLEN * NB * VOC);
    float* Za     = (float*)(Epk + (size_t)(VOC / 2) * VOC);
    float* Zb     = Za + (size_t)NB * VOC;
    unsigned int* cnt = (unsigned int*)(Zb + (size_t)NB * VOC);

    (void)hipMemsetAsync(cnt, 0, TLEN * 16 * sizeof(unsigned int), stream);
    gemm_logits2<<<dim3(VOC / 128, TLEN * NB / 128), 256, 0, stream>>>(enc, W, bias, logits);
    exp_pack<<<dim3((VOC / 2) * VOC / 256), 256, 0, stream>>>(trans, Epk);
    crf_scan<<<dim3(16, 16), 512, 0, stream>>>(logits, Za, Zb, Epk, lengths, cnt);
    crf_finish<<<1, 256, 0, stream>>>(Za, logits, trans, targets, lengths, out);
}

// Round 8
// 1061.138 us; speedup vs baseline: 4.7928x; 1.0106x over previous
//
#include <hip/hip_runtime.h>
#include <math.h>
#include <stdint.h>

#define TLEN 256
#define NB   32
#define HID  512
#define VOC  1024

typedef __attribute__((ext_vector_type(2))) _Float16 half2_t;
typedef __attribute__((ext_vector_type(2))) __fp16  pk16_t;

// ---- device-coherent (agent-scope) Z accessors ----
__device__ __forceinline__ float zload(const float* p) {
    return __hip_atomic_load(p, __ATOMIC_RELAXED, __HIP_MEMORY_SCOPE_AGENT);
}
__device__ __forceinline__ float2 zload2(const float* p) {
    unsigned long long u = __hip_atomic_load((const unsigned long long*)p,
                                             __ATOMIC_RELAXED, __HIP_MEMORY_SCOPE_AGENT);
    union { unsigned long long u; float2 f; } c; c.u = u; return c.f;
}
__device__ __forceinline__ void zstore(float* p, float v) {
    __hip_atomic_store(p, v, __ATOMIC_RELAXED, __HIP_MEMORY_SCOPE_AGENT);
}
__device__ __forceinline__ uint32_t pack_pkrtz(float a, float b) {
    pk16_t h = __builtin_amdgcn_cvt_pkrtz(a, b);
    return __builtin_bit_cast(uint32_t, h);
}
__device__ __forceinline__ float fdot2u(uint32_t a, uint32_t b, float acc) {
    half2_t ha = __builtin_bit_cast(half2_t, a);
    half2_t hb = __builtin_bit_cast(half2_t, b);
    return __builtin_amdgcn_fdot2(ha, hb, acc, false);
}

// ---------------- GEMM: logits = enc @ W^T + bias ----------------
__global__ __launch_bounds__(256) void gemm_logits2(
    const float* __restrict__ A, const float* __restrict__ W,
    const float* __restrict__ bias, float* __restrict__ C)
{
    const int K = HID, N = VOC;
    __shared__ float As[16][132];
    __shared__ float Ws[16][132];
    int tid = threadIdx.x;
    int row0 = blockIdx.y << 7;
    int col0 = blockIdx.x << 7;
    int tx = tid & 15, ty = tid >> 4;
    int lr = tid >> 2;
    int lk = (tid & 3) << 2;
    float acc[8][8] = {};
    float bj[8];
    #pragma unroll
    for (int j = 0; j < 8; ++j) bj[j] = bias[col0 + tx * 8 + j];

    for (int k0 = 0; k0 < K; k0 += 16) {
        float4 av0 = *(const float4*)(A + (size_t)(row0 + lr) * K + k0 + lk);
        float4 av1 = *(const float4*)(A + (size_t)(row0 + lr + 64) * K + k0 + lk);
        float4 wv0 = *(const float4*)(W + (size_t)(col0 + lr) * K + k0 + lk);
        float4 wv1 = *(const float4*)(W + (size_t)(col0 + lr + 64) * K + k0 + lk);
        __syncthreads();
        As[lk+0][lr] = av0.x; As[lk+1][lr] = av0.y; As[lk+2][lr] = av0.z; As[lk+3][lr] = av0.w;
        As[lk+0][lr+64] = av1.x; As[lk+1][lr+64] = av1.y; As[lk+2][lr+64] = av1.z; As[lk+3][lr+64] = av1.w;
        Ws[lk+0][lr] = wv0.x; Ws[lk+1][lr] = wv0.y; Ws[lk+2][lr] = wv0.z; Ws[lk+3][lr] = wv0.w;
        Ws[lk+0][lr+64] = wv1.x; Ws[lk+1][lr+64] = wv1.y; Ws[lk+2][lr+64] = wv1.z; Ws[lk+3][lr+64] = wv1.w;
        __syncthreads();
        #pragma unroll
        for (int k = 0; k < 16; ++k) {
            float4 a0 = *(const float4*)&As[k][ty * 8];
            float4 a1 = *(const float4*)&As[k][ty * 8 + 4];
            float4 w0 = *(const float4*)&Ws[k][tx * 8];
            float4 w1 = *(const float4*)&Ws[k][tx * 8 + 4];
            float ar[8] = {a0.x, a0.y, a0.z, a0.w, a1.x, a1.y, a1.z, a1.w};
            float wr[8] = {w0.x, w0.y, w0.z, w0.w, w1.x, w1.y, w1.z, w1.w};
            #pragma unroll
            for (int i = 0; i < 8; ++i)
                #pragma unroll
                for (int j = 0; j < 8; ++j)
                    acc[i][j] = fmaf(ar[i], wr[j], acc[i][j]);
        }
    }
    #pragma unroll
    for (int i = 0; i < 8; ++i) {
        size_t r = row0 + ty * 8 + i;
        float4 o0, o1;
        o0.x = acc[i][0] + bj[0]; o0.y = acc[i][1] + bj[1];
        o0.z = acc[i][2] + bj[2]; o0.w = acc[i][3] + bj[3];
        o1.x = acc[i][4] + bj[4]; o1.y = acc[i][5] + bj[5];
        o1.z = acc[i][6] + bj[6]; o1.w = acc[i][7] + bj[7];
        *(float4*)(C + r * N + col0 + tx * 8)     = o0;
        *(float4*)(C + r * N + col0 + tx * 8 + 4) = o1;
    }
}

// ---------------- Epk[v2][c] = half2(exp(trans[2v2][c]), exp(trans[2v2+1][c])) ----------------
__global__ __launch_bounds__(256) void exp_pack(
    const float* __restrict__ trans, uint32_t* __restrict__ Epk)
{
    int idx = blockIdx.x * 256 + threadIdx.x;       // over 512*1024
    int v2 = idx >> 10, c = idx & 1023;
    float e0 = __expf(trans[(size_t)(2 * v2) * VOC + c]);
    float e1 = __expf(trans[(size_t)(2 * v2 + 1) * VOC + c]);
    Epk[idx] = pack_pkrtz(e0, e1);
}

// ---------------- persistent CRF scan v5 ----------------
// grid (16 bg, 16 cc), 512 thr = 8 waves; block = batches {2bg,2bg+1} x 64 cols.
// v5: staging distributed over all 8 waves (2 zload2/lane, two-phase max via LDS);
// finalize operand prefetched before the dot2 loop. m cancels exactly in
// m + log(S), so it only guards overflow (f16 p needs z-m <= ~11).
__global__ __launch_bounds__(512) void crf_scan(
    const float* __restrict__ logits, float* __restrict__ Za, float* __restrict__ Zb,
    const uint32_t* __restrict__ Epk, const int* __restrict__ lengths,
    unsigned int* __restrict__ cnt)
{
    __shared__ uint32_t pst[VOC / 2][2];   // 4 KB: [v2][local batch] packed half2
    __shared__ float pmax[8][2];           // per-wave partial row maxes
    __shared__ float Sred[8][64][3];       // [wave][col][batch], +1 pad
    int tid  = threadIdx.x;
    int w    = tid >> 6;
    int lane = tid & 63;
    int bg   = blockIdx.x;                 // linear = bg + 16*cc
    int cc   = blockIdx.y;
    int b0   = bg * 2;

    int len2[2];
    len2[0] = lengths[b0];
    len2[1] = lengths[b0 + 1];
    int lmax = max(len2[0], len2[1]);

    int v2s = (w << 6) + lane;             // staging slot: v2 in [0,512)
    int c   = (cc << 6) + lane;            // compute/finalize column

    const float* src = logits;             // Z0 = logits[t=0] (rows 0..31)
    for (int t = 1; t < TLEN; ++t) {
        float* dst = (t & 1) ? Za : Zb;
        if (t >= lmax) {                   // uniform across this bg's 16 blocks
            if (src != Za && tid < 128) {  // park final Z into Za
                int b = b0 + w;
                Za[(size_t)b * VOC + c] = zload(&src[(size_t)b * VOC + c]);
            }
            return;
        }
        // (A) distributed staging: each thread loads 2 v of both batches
        float2 z0 = zload2(&src[(size_t)b0 * VOC + 2 * v2s]);
        float2 z1 = zload2(&src[(size_t)(b0 + 1) * VOC + 2 * v2s]);
        float pm0 = fmaxf(z0.x, z0.y);
        float pm1 = fmaxf(z1.x, z1.y);
        #pragma unroll
        for (int off = 32; off; off >>= 1) {
            pm0 = fmaxf(pm0, __shfl_xor(pm0, off));
            pm1 = fmaxf(pm1, __shfl_xor(pm1, off));
        }
        if (lane == 0) { pmax[w][0] = pm0; pmax[w][1] = pm1; }
        __syncthreads();
        float m0 = pmax[0][0], m1 = pmax[0][1];
        #pragma unroll
        for (int ww = 1; ww < 8; ++ww) {
            m0 = fmaxf(m0, pmax[ww][0]);
            m1 = fmaxf(m1, pmax[ww][1]);
        }
        uint2 pp;
        pp.x = pack_pkrtz(__expf(z0.x - m0), __expf(z0.y - m0));
        pp.y = pack_pkrtz(__expf(z1.x - m1), __expf(z1.y - m1));
        *(uint2*)&pst[v2s][0] = pp;

        // prefetch finalize operand (hides L2/HBM latency under the dot2 loop)
        float fin = 0.f;
        if (tid < 128) {
            int b = b0 + w;
            if (t < len2[w]) fin = logits[((size_t)t * NB + b) * VOC + c];
            else             fin = zload(&src[(size_t)b * VOC + c]);
        }
        __syncthreads();                   // pst complete

        // (C) wave w: partial S over v2 in [w*64, w*64+64), 64 cols x 2 batches
        const uint32_t* Ep = Epk + c;
        int v20 = w << 6;
        float a0 = 0.f, a1 = 0.f;
        #pragma unroll 8
        for (int j = 0; j < 64; j += 2) {
            int v2 = v20 + j;
            uint4 pq = *(const uint4*)&pst[v2][0];        // (v2,b0)(v2,b1)(v2+1,b0)(v2+1,b1)
            uint32_t e0 = Ep[(size_t)v2 << 10];
            uint32_t e1 = Ep[(size_t)(v2 + 1) << 10];
            a0 = fdot2u(pq.x, e0, a0);
            a1 = fdot2u(pq.y, e0, a1);
            a0 = fdot2u(pq.z, e1, a0);
            a1 = fdot2u(pq.w, e1, a1);
        }
        Sred[w][lane][0] = a0;
        Sred[w][lane][1] = a1;
        __syncthreads();                   // (D)

        // (E) finalize: 128 threads, 2 batches x 64 cols
        if (tid < 128) {
            float S = 0.f;
            #pragma unroll
            for (int ww = 0; ww < 8; ++ww) S += Sred[ww][lane][w];
            int b = b0 + w;
            float outv;
            if (t < len2[w]) outv = fin + (w ? m1 : m0) + __logf(S);
            else             outv = fin;
            zstore(&dst[(size_t)b * VOC + c], outv);
        }

        // (F) inter-block barrier among this bg's 16 blocks
        __syncthreads();                   // drains vmcnt(0): Z stores visible
        if (tid == 0) {
            unsigned int* c16 = &cnt[t * 16 + bg];
            __hip_atomic_fetch_add(c16, 1u, __ATOMIC_RELAXED, __HIP_MEMORY_SCOPE_AGENT);
            while (__hip_atomic_load(c16, __ATOMIC_RELAXED, __HIP_MEMORY_SCOPE_AGENT) < 16u)
                __builtin_amdgcn_s_sleep(1);
        }
        __syncthreads();
        src = dst;
    }
}

// ---------------- epilogue ----------------
__global__ __launch_bounds__(256) void crf_finish(
    const float* __restrict__ Zfin, const float* __restrict__ logits,
    const float* __restrict__ trans, const int* __restrict__ targets,
    const int* __restrict__ lengths, float* __restrict__ out)
{
    __shared__ float part[NB];
    int tid = threadIdx.x;
    int b = tid >> 3, j = tid & 7;
    const float* zr = Zfin + (size_t)b * VOC;
    float m = -1e30f;
    for (int v = j; v < VOC; v += 8) m = fmaxf(m, zr[v]);
    #pragma unroll
    for (int off = 1; off < 8; off <<= 1) m = fmaxf(m, __shfl_xor(m, off));
    float s = 0.f;
    for (int v = j; v < VOC; v += 8) s += __expf(zr[v] - m);
    #pragma unroll
    for (int off = 1; off < 8; off <<= 1) s += __shfl_xor(s, off);
    float logZ = m + __logf(s);
    int len = lengths[b];
    float acc = 0.f;
    for (int t = j; t < TLEN; t += 8) {
        if (t < len) {
            int tg = targets[t * NB + b];
            acc += logits[((size_t)t * NB + b) * VOC + tg];
            if (t >= 1) acc += trans[(size_t)targets[(t - 1) * NB + b] * VOC + tg];
        }
    }
    #pragma unroll
    for (int off = 1; off < 8; off <<= 1) acc += __shfl_xor(acc, off);
    if (j == 0) part[b] = logZ - acc;
    __syncthreads();
    if (tid == 0) {
        float sum = 0.f;
        #pragma unroll
        for (int i = 0; i < NB; ++i) sum += part[i];
        out[0] = sum / (float)NB;
    }
}

extern "C" void kernel_launch(void* const* d_in, const int* in_sizes, int n_in,
                              void* d_out, int out_size, void* d_ws, size_t ws_size,
                              hipStream_t stream)
{
    const float* enc   = (const float*)d_in[0];
    const float* W     = (const float*)d_in[1];
    const float* bias  = (const float*)d_in[2];
    const float* trans = (const float*)d_in[3];
    const int* targets = (const int*)d_in[4];
    const int* lengths = (const int*)d_in[5];
    float* out = (float*)d_out;

    // ws: logits 33.5MB | Epk 2MB | Za 128KB | Zb 128KB | cnt 16KB
    float* ws     = (float*)d_ws;
    float* logits = ws;
    uint32_t* Epk = (uint32_t*)(logits + (size_t)TLEN * NB * VOC);
    float* Za     = (float*)(Epk + (size_t)(VOC / 2) * VOC);
    float* Zb     = Za + (size_t)NB * VOC;
    unsigned int* cnt = (unsigned int*)(Zb + (size_t)NB * VOC);

    (void)hipMemsetAsync(cnt, 0, TLEN * 16 * sizeof(unsigned int), stream);
    gemm_logits2<<<dim3(VOC / 128, TLEN * NB / 128), 256, 0, stream>>>(enc, W, bias, logits);
    exp_pack<<<dim3((VOC / 2) * VOC / 256), 256, 0, stream>>>(trans, Epk);
    crf_scan<<<dim3(16, 16), 512, 0, stream>>>(logits, Za, Zb, Epk, lengths, cnt);
    crf_finish<<<1, 256, 0, stream>>>(Za, logits, trans, targets, lengths, out);
}

// Round 9
// 1025.695 us; speedup vs baseline: 4.9585x; 1.0346x over previous
//
#include <hip/hip_runtime.h>
#include <math.h>
#include <stdint.h>

#define TLEN 256
#define NB   32
#define HID  512
#define VOC  1024

typedef __attribute__((ext_vector_type(2))) _Float16 half2_t;
typedef __attribute__((ext_vector_type(2))) __fp16  pk16_t;

// ---- device-coherent (agent-scope) Z accessors ----
__device__ __forceinline__ float zload(const float* p) {
    return __hip_atomic_load(p, __ATOMIC_RELAXED, __HIP_MEMORY_SCOPE_AGENT);
}
__device__ __forceinline__ float2 zload2(const float* p) {
    unsigned long long u = __hip_atomic_load((const unsigned long long*)p,
                                             __ATOMIC_RELAXED, __HIP_MEMORY_SCOPE_AGENT);
    union { unsigned long long u; float2 f; } c; c.u = u; return c.f;
}
__device__ __forceinline__ void zstore(float* p, float v) {
    __hip_atomic_store(p, v, __ATOMIC_RELAXED, __HIP_MEMORY_SCOPE_AGENT);
}
__device__ __forceinline__ uint32_t pack_pkrtz(float a, float b) {
    pk16_t h = __builtin_amdgcn_cvt_pkrtz(a, b);
    return __builtin_bit_cast(uint32_t, h);
}
__device__ __forceinline__ float fdot2u(uint32_t a, uint32_t b, float acc) {
    half2_t ha = __builtin_bit_cast(half2_t, a);
    half2_t hb = __builtin_bit_cast(half2_t, b);
    return __builtin_amdgcn_fdot2(ha, hb, acc, false);
}

// ---------------- GEMM v3: logits = enc @ W^T + bias, f16 dot2 inner ----------------
// A,W staged in LDS as half2 packed over k. Halves VALU instrs and LDS reads vs fp32.
__global__ __launch_bounds__(256) void gemm_logits3(
    const float* __restrict__ A, const float* __restrict__ W,
    const float* __restrict__ bias, float* __restrict__ C)
{
    const int K = HID, N = VOC;
    __shared__ uint32_t As2[8][132];   // [k-pair][row]
    __shared__ uint32_t Ws2[8][132];   // [k-pair][col]
    int tid = threadIdx.x;
    int row0 = blockIdx.y << 7;
    int col0 = blockIdx.x << 7;
    int tx = tid & 15, ty = tid >> 4;
    int lr = tid >> 2;
    int lk = (tid & 3) << 2;           // k offset 0,4,8,12
    int kp0 = lk >> 1;                 // k-pair index 0,2,4,6
    float acc[8][8] = {};
    float bj[8];
    #pragma unroll
    for (int j = 0; j < 8; ++j) bj[j] = bias[col0 + tx * 8 + j];

    for (int k0 = 0; k0 < K; k0 += 16) {
        float4 av0 = *(const float4*)(A + (size_t)(row0 + lr) * K + k0 + lk);
        float4 av1 = *(const float4*)(A + (size_t)(row0 + lr + 64) * K + k0 + lk);
        float4 wv0 = *(const float4*)(W + (size_t)(col0 + lr) * K + k0 + lk);
        float4 wv1 = *(const float4*)(W + (size_t)(col0 + lr + 64) * K + k0 + lk);
        __syncthreads();
        As2[kp0][lr]      = pack_pkrtz(av0.x, av0.y);
        As2[kp0+1][lr]    = pack_pkrtz(av0.z, av0.w);
        As2[kp0][lr+64]   = pack_pkrtz(av1.x, av1.y);
        As2[kp0+1][lr+64] = pack_pkrtz(av1.z, av1.w);
        Ws2[kp0][lr]      = pack_pkrtz(wv0.x, wv0.y);
        Ws2[kp0+1][lr]    = pack_pkrtz(wv0.z, wv0.w);
        Ws2[kp0][lr+64]   = pack_pkrtz(wv1.x, wv1.y);
        Ws2[kp0+1][lr+64] = pack_pkrtz(wv1.z, wv1.w);
        __syncthreads();
        #pragma unroll
        for (int kp = 0; kp < 8; ++kp) {
            uint4 a0 = *(const uint4*)&As2[kp][ty * 8];
            uint4 a1 = *(const uint4*)&As2[kp][ty * 8 + 4];
            uint4 w0 = *(const uint4*)&Ws2[kp][tx * 8];
            uint4 w1 = *(const uint4*)&Ws2[kp][tx * 8 + 4];
            uint32_t ar[8] = {a0.x, a0.y, a0.z, a0.w, a1.x, a1.y, a1.z, a1.w};
            uint32_t wr[8] = {w0.x, w0.y, w0.z, w0.w, w1.x, w1.y, w1.z, w1.w};
            #pragma unroll
            for (int i = 0; i < 8; ++i)
                #pragma unroll
                for (int j = 0; j < 8; ++j)
                    acc[i][j] = fdot2u(ar[i], wr[j], acc[i][j]);
        }
    }
    #pragma unroll
    for (int i = 0; i < 8; ++i) {
        size_t r = row0 + ty * 8 + i;
        float4 o0, o1;
        o0.x = acc[i][0] + bj[0]; o0.y = acc[i][1] + bj[1];
        o0.z = acc[i][2] + bj[2]; o0.w = acc[i][3] + bj[3];
        o1.x = acc[i][4] + bj[4]; o1.y = acc[i][5] + bj[5];
        o1.z = acc[i][6] + bj[6]; o1.w = acc[i][7] + bj[7];
        *(float4*)(C + r * N + col0 + tx * 8)     = o0;
        *(float4*)(C + r * N + col0 + tx * 8 + 4) = o1;
    }
}

// ---------------- Epk[v2][c] = half2(exp(trans[2v2][c]), exp(trans[2v2+1][c])) ----------------
__global__ __launch_bounds__(256) void exp_pack(
    const float* __restrict__ trans, uint32_t* __restrict__ Epk)
{
    int idx = blockIdx.x * 256 + threadIdx.x;       // over 512*1024
    int v2 = idx >> 10, c = idx & 1023;
    float e0 = __expf(trans[(size_t)(2 * v2) * VOC + c]);
    float e1 = __expf(trans[(size_t)(2 * v2 + 1) * VOC + c]);
    Epk[idx] = pack_pkrtz(e0, e1);
}

// ---------------- persistent CRF scan v6: p via readlane (no LDS in hot loop) ----------------
// grid (16 bg, 16 cc), 512 thr = 8 waves. Wave w covers v2 in [w*64, w*64+64);
// lane l stages p-pair v2 = w*64+l into registers; compute broadcasts them with
// v_readlane into SGPRs (fully unrolled, constant lane) -> dot2 with SGPR operand.
// LDS used only for pmax/Sred reductions. DS pipe out of the critical loop.
__global__ __launch_bounds__(512) void crf_scan(
    const float* __restrict__ logits, float* __restrict__ Za, float* __restrict__ Zb,
    const uint32_t* __restrict__ Epk, const int* __restrict__ lengths,
    unsigned int* __restrict__ cnt)
{
    __shared__ float pmax[8][2];
    __shared__ float Sred[8][64][3];
    int tid  = threadIdx.x;
    int w    = tid >> 6;
    int lane = tid & 63;
    int bg   = blockIdx.x;                 // linear = bg + 16*cc -> XCD = bg%8: group shares XCD
    int cc   = blockIdx.y;
    int b0   = bg * 2;

    int len2[2];
    len2[0] = lengths[b0];
    len2[1] = lengths[b0 + 1];
    int lmax = max(len2[0], len2[1]);

    int v2s = (w << 6) + lane;             // this thread's staged v2
    int c   = (cc << 6) + lane;            // compute/finalize column
    const uint32_t* Ec = Epk + c + ((size_t)(w << 6) << 10);  // wave's E slice base

    const float* src = logits;             // Z0 = logits[t=0] (rows 0..31)
    for (int t = 1; t < TLEN; ++t) {
        float* dst = (t & 1) ? Za : Zb;
        if (t >= lmax) {                   // uniform across this bg's 16 blocks
            if (src != Za && tid < 128) {  // park final Z into Za
                int b = b0 + w;
                Za[(size_t)b * VOC + c] = zload(&src[(size_t)b * VOC + c]);
            }
            return;
        }
        // (A) staging: thread loads 2 v of both batches, block max via LDS
        float2 z0 = zload2(&src[(size_t)b0 * VOC + 2 * v2s]);
        float2 z1 = zload2(&src[(size_t)(b0 + 1) * VOC + 2 * v2s]);
        float pm0 = fmaxf(z0.x, z0.y);
        float pm1 = fmaxf(z1.x, z1.y);
        #pragma unroll
        for (int off = 32; off; off >>= 1) {
            pm0 = fmaxf(pm0, __shfl_xor(pm0, off));
            pm1 = fmaxf(pm1, __shfl_xor(pm1, off));
        }
        if (lane == 0) { pmax[w][0] = pm0; pmax[w][1] = pm1; }
        __syncthreads();
        float m0 = pmax[0][0], m1 = pmax[0][1];
        #pragma unroll
        for (int ww = 1; ww < 8; ++ww) {
            m0 = fmaxf(m0, pmax[ww][0]);
            m1 = fmaxf(m1, pmax[ww][1]);
        }
        uint32_t pp0 = pack_pkrtz(__expf(z0.x - m0), __expf(z0.y - m0));
        uint32_t pp1 = pack_pkrtz(__expf(z1.x - m1), __expf(z1.y - m1));

        // prefetch finalize operand (hides L2 latency under the dot2 loop)
        float fin = 0.f;
        if (tid < 128) {
            int b = b0 + w;
            if (t < len2[w]) fin = logits[((size_t)t * NB + b) * VOC + c];
            else             fin = zload(&src[(size_t)b * VOC + c]);
        }

        // (C) compute: 64 v2 per wave; p broadcast lane->SGPR via readlane
        float a0 = 0.f, a1 = 0.f;
        #pragma unroll
        for (int j = 0; j < 64; ++j) {
            uint32_t s0 = (uint32_t)__builtin_amdgcn_readlane((int)pp0, j);
            uint32_t s1 = (uint32_t)__builtin_amdgcn_readlane((int)pp1, j);
            uint32_t e  = Ec[(size_t)j << 10];
            a0 = fdot2u(e, s0, a0);
            a1 = fdot2u(e, s1, a1);
        }
        Sred[w][lane][0] = a0;
        Sred[w][lane][1] = a1;
        __syncthreads();                   // (D)

        // (E) finalize: 128 threads, 2 batches x 64 cols
        if (tid < 128) {
            float S = 0.f;
            #pragma unroll
            for (int ww = 0; ww < 8; ++ww) S += Sred[ww][lane][w];
            int b = b0 + w;
            float outv;
            if (t < len2[w]) outv = fin + (w ? m1 : m0) + __logf(S);
            else             outv = fin;
            zstore(&dst[(size_t)b * VOC + c], outv);
        }

        // (F) inter-block barrier among this bg's 16 blocks (same XCD)
        __syncthreads();                   // drains vmcnt(0): Z stores visible
        if (tid == 0) {
            unsigned int* c16 = &cnt[t * 16 + bg];
            __hip_atomic_fetch_add(c16, 1u, __ATOMIC_RELAXED, __HIP_MEMORY_SCOPE_AGENT);
            while (__hip_atomic_load(c16, __ATOMIC_RELAXED, __HIP_MEMORY_SCOPE_AGENT) < 16u)
                __builtin_amdgcn_s_sleep(1);
        }
        __syncthreads();
        src = dst;
    }
}

// ---------------- epilogue ----------------
__global__ __launch_bounds__(256) void crf_finish(
    const float* __restrict__ Zfin, const float* __restrict__ logits,
    const float* __restrict__ trans, const int* __restrict__ targets,
    const int* __restrict__ lengths, float* __restrict__ out)
{
    __shared__ float part[NB];
    int tid = threadIdx.x;
    int b = tid >> 3, j = tid & 7;
    const float* zr = Zfin + (size_t)b * VOC;
    float m = -1e30f;
    for (int v = j; v < VOC; v += 8) m = fmaxf(m, zr[v]);
    #pragma unroll
    for (int off = 1; off < 8; off <<= 1) m = fmaxf(m, __shfl_xor(m, off));
    float s = 0.f;
    for (int v = j; v < VOC; v += 8) s += __expf(zr[v] - m);
    #pragma unroll
    for (int off = 1; off < 8; off <<= 1) s += __shfl_xor(s, off);
    float logZ = m + __logf(s);
    int len = lengths[b];
    float acc = 0.f;
    for (int t = j; t < TLEN; t += 8) {
        if (t < len) {
            int tg = targets[t * NB + b];
            acc += logits[((size_t)t * NB + b) * VOC + tg];
            if (t >= 1) acc += trans[(size_t)targets[(t - 1) * NB + b] * VOC + tg];
        }
    }
    #pragma unroll
    for (int off = 1; off < 8; off <<= 1) acc += __shfl_xor(acc, off);
    if (j == 0) part[b] = logZ - acc;
    __syncthreads();
    if (tid == 0) {
        float sum = 0.f;
        #pragma unroll
        for (int i = 0; i < NB; ++i) sum += part[i];
        out[0] = sum / (float)NB;
    }
}

extern "C" void kernel_launch(void* const* d_in, const int* in_sizes, int n_in,
                              void* d_out, int out_size, void* d_ws, size_t ws_size,
                              hipStream_t stream)
{
    const float* enc   = (const float*)d_in[0];
    const float* W     = (const float*)d_in[1];
    const float* bias  = (const float*)d_in[2];
    const float* trans = (const float*)d_in[3];
    const int* targets = (const int*)d_in[4];
    const int* lengths = (const int*)d_in[5];
    float* out = (float*)d_out;

    // ws: logits 33.5MB | Epk 2MB | Za 128KB | Zb 128KB | cnt 16KB
    float* ws     = (float*)d_ws;
    float* logits = ws;
    uint32_t* Epk = (uint32_t*)(logits + (size_t)TLEN * NB * VOC);
    float* Za     = (float*)(Epk + (size_t)(VOC / 2) * VOC);
    float* Zb     = Za + (size_t)NB * VOC;
    unsigned int* cnt = (unsigned int*)(Zb + (size_t)NB * VOC);

    (void)hipMemsetAsync(cnt, 0, TLEN * 16 * sizeof(unsigned int), stream);
    gemm_logits3<<<dim3(VOC / 128, TLEN * NB / 128), 256, 0, stream>>>(enc, W, bias, logits);
    exp_pack<<<dim3((VOC / 2) * VOC / 256), 256, 0, stream>>>(trans, Epk);
    crf_scan<<<dim3(16, 16), 512, 0, stream>>>(logits, Za, Zb, Epk, lengths, cnt);
    crf_finish<<<1, 256, 0, stream>>>(Za, logits, trans, targets, lengths, out);
}